// Round 16
// baseline (293.267 us; speedup 1.0000x reference)
//
#include <hip/hip_runtime.h>
#include <hip/hip_bf16.h>

typedef __attribute__((ext_vector_type(8))) short short8;
typedef __attribute__((ext_vector_type(4))) short short4v;
typedef __attribute__((ext_vector_type(4))) float f32x4;

#define Dk 1024
#define TT 2048
#define BB 8
#define MROWS (BB * TT)   // 16384
#define LOG2E 1.44269504088896f

#if defined(__has_builtin)
#if __has_builtin(__builtin_amdgcn_rcpf)
#define FAST_RCP(x) __builtin_amdgcn_rcpf(x)
#endif
#if __has_builtin(__builtin_amdgcn_exp2f)
#define FAST_EXP2(x) __builtin_amdgcn_exp2f(x)
#endif
#endif
#ifndef FAST_RCP
#define FAST_RCP(x) (1.f / (x))
#endif
#ifndef FAST_EXP2
#define FAST_EXP2(x) exp2f(x)
#endif

#define BAR()   __builtin_amdgcn_s_barrier()
#define LGKM0() do { asm volatile("s_waitcnt lgkmcnt(0)" ::: "memory"); \
                     __builtin_amdgcn_sched_barrier(0); } while (0)

__device__ __forceinline__ void gload_lds16(const void* g, void* l) {
    __builtin_amdgcn_global_load_lds(
        (const __attribute__((address_space(1))) void*)g,
        (__attribute__((address_space(3))) void*)l, 16, 0, 0);
}

__device__ __forceinline__ float sigmoidf_fast(float x) {
    return FAST_RCP(1.f + FAST_EXP2(-x * LOG2E));
}

__device__ __forceinline__ unsigned short bf16_bits(float x) {
    union { __hip_bfloat16 h; unsigned short u; } c;
    c.h = __float2bfloat16(x);
    return c.u;
}

// One launch converts x (16384 chunk-blocks) + 4 weights (1024 each).
__global__ __launch_bounds__(256)
void cvt_all(const float* __restrict__ x,
             const float* __restrict__ w0, const float* __restrict__ w1,
             const float* __restrict__ w2, const float* __restrict__ w3,
             __hip_bfloat16* __restrict__ xo,
             __hip_bfloat16* __restrict__ o0, __hip_bfloat16* __restrict__ o1,
             __hip_bfloat16* __restrict__ o2, __hip_bfloat16* __restrict__ o3)
{
    const int bid = blockIdx.x;
    const float* in;
    __hip_bfloat16* out;
    int base;
    if (bid < 16384) {
        in = x; out = xo; base = bid * 1024;
    } else {
        const int wbid  = bid - 16384;
        const int which = wbid >> 10;
        in  = which == 0 ? w0 : which == 1 ? w1 : which == 2 ? w2 : w3;
        out = which == 0 ? o0 : which == 1 ? o1 : which == 2 ? o2 : o3;
        base = (wbid & 1023) * 1024;
    }
    const int i = base + threadIdx.x * 4;
    const float4 v = *(const float4*)(in + i);
    __hip_bfloat16 tmp[4];
    tmp[0] = __float2bfloat16(v.x);
    tmp[1] = __float2bfloat16(v.y);
    tmp[2] = __float2bfloat16(v.z);
    tmp[3] = __float2bfloat16(v.w);
    *(short4v*)(out + i) = *(const short4v*)tmp;
}

// 256x256-tile 8-wave GEMM, C = epi(A * B^T), 8-phase schedule (r14-proven).
// EPI: 0 silu->bf16 | 1 plain->f32 | 6 E=exp(-(x+b_al))->bf16 (contiguous)
//      7 Vt=tanh(x+b_v)*nl2->bf16 (contiguous)
template<int EPI>
__global__ __launch_bounds__(512)
void gemm256(const __hip_bfloat16* __restrict__ A,
             const __hip_bfloat16* __restrict__ Bw,
             const float* __restrict__ bias,
             const float* __restrict__ dal,     // EPI7 only
             void* __restrict__ CoutV)
{
    __shared__ __align__(16) char lds[2 * 65536];   // buf: A 32KB | B 32KB

    const int tid  = threadIdx.x;         // 0..511
    const int bid  = blockIdx.x;
    const int nbid = (bid & 7) * 32 + (bid >> 3);   // XCD swizzle (256%8==0)
    const int tn   = nbid & 3;            // 4 col tiles
    const int tm   = nbid >> 2;           // 64 row tiles
    const int lane = tid & 63;
    const int w    = tid >> 6;            // 0..7
    const int wm   = w >> 2;              // 0..1
    const int wn   = w & 3;               // 0..3
    const int l15  = lane & 15;
    const int lq   = lane >> 4;

    const __hip_bfloat16* Ap = A  + (size_t)(tm * 256) * Dk;
    const __hip_bfloat16* Bp = Bw + (size_t)(tn * 256) * Dk;

    const int rA = wm * 16384 + l15 * 128;
    const int rB = 32768 + wn * 8192 + l15 * 128;
    int c8k[2];
    c8k[0] = ((lq    ) ^ (l15 & 7)) * 16;
    c8k[1] = ((lq + 4) ^ (l15 & 7)) * 16;

    const int srow = tid >> 3;
    const int scol = ((tid & 7) ^ (srow & 7)) * 8;

    auto stageHalf = [&](const __hip_bfloat16* src0, int reg, int h, int kt, int bb) {
#pragma unroll
        for (int j = 0; j < 2; ++j) {
            const int row  = h * 128 + j * 64 + srow;
            const int slot = h * 1024 + j * 512 + tid;
            gload_lds16(src0 + (size_t)row * Dk + kt * 64 + scol,
                        (char*)lds + bb + reg * 32768 + slot * 16);
        }
    };

    f32x4 acc[8][4];
#pragma unroll
    for (int m = 0; m < 8; ++m)
#pragma unroll
        for (int n = 0; n < 4; ++n)
            acc[m][n] = (f32x4){0.f, 0.f, 0.f, 0.f};

    stageHalf(Ap, 0, 0, 0, 0);      stageHalf(Ap, 0, 1, 0, 0);
    stageHalf(Bp, 1, 0, 0, 0);      stageHalf(Bp, 1, 1, 0, 0);
    stageHalf(Bp, 1, 0, 1, 65536);  stageHalf(Bp, 1, 1, 1, 65536);
    asm volatile("s_waitcnt vmcnt(4)" ::: "memory");
    BAR();

    short8 a[4][2], bfr[4][2];

    for (int t = 0; t < 16; ++t) {
        const int bb = (t & 1) * 65536;
        const int nb = bb ^ 65536;
        const char* cb = (const char*)lds + bb;

        // phase 1: A m0-3 + B n0-1 reads; stage A.h0(t+1)
#pragma unroll
        for (int m = 0; m < 4; ++m)
#pragma unroll
            for (int kk = 0; kk < 2; ++kk)
                a[m][kk] = *(const short8*)(cb + rA + m * 2048 + c8k[kk]);
#pragma unroll
        for (int n = 0; n < 2; ++n)
#pragma unroll
            for (int kk = 0; kk < 2; ++kk)
                bfr[n][kk] = *(const short8*)(cb + rB + n * 2048 + c8k[kk]);
        if (t + 1 < 16) stageHalf(Ap, 0, 0, t + 1, nb);
        BAR(); LGKM0();
        __builtin_amdgcn_s_setprio(1);
#pragma unroll
        for (int m = 0; m < 4; ++m)
#pragma unroll
            for (int n = 0; n < 2; ++n)
#pragma unroll
                for (int kk = 0; kk < 2; ++kk)
                    acc[m][n] = __builtin_amdgcn_mfma_f32_16x16x32_bf16(
                        a[m][kk], bfr[n][kk], acc[m][n], 0, 0, 0);
        __builtin_amdgcn_s_setprio(0);
        BAR();

        // phase 2: B n2-3 reads; stage A.h1(t+1)
#pragma unroll
        for (int n = 2; n < 4; ++n)
#pragma unroll
            for (int kk = 0; kk < 2; ++kk)
                bfr[n][kk] = *(const short8*)(cb + rB + n * 2048 + c8k[kk]);
        if (t + 1 < 16) stageHalf(Ap, 0, 1, t + 1, nb);
        BAR(); LGKM0();
        __builtin_amdgcn_s_setprio(1);
#pragma unroll
        for (int m = 0; m < 4; ++m)
#pragma unroll
            for (int n = 2; n < 4; ++n)
#pragma unroll
                for (int kk = 0; kk < 2; ++kk)
                    acc[m][n] = __builtin_amdgcn_mfma_f32_16x16x32_bf16(
                        a[m][kk], bfr[n][kk], acc[m][n], 0, 0, 0);
        __builtin_amdgcn_s_setprio(0);
        BAR();

        // phase 3: A m4-7 reads (reuse regs); stage B.h0(t+2)
#pragma unroll
        for (int m = 0; m < 4; ++m)
#pragma unroll
            for (int kk = 0; kk < 2; ++kk)
                a[m][kk] = *(const short8*)(cb + rA + (m + 4) * 2048 + c8k[kk]);
        if (t + 2 < 16) stageHalf(Bp, 1, 0, t + 2, bb);
        BAR(); LGKM0();
        __builtin_amdgcn_s_setprio(1);
#pragma unroll
        for (int m = 0; m < 4; ++m)
#pragma unroll
            for (int n = 0; n < 2; ++n)
#pragma unroll
                for (int kk = 0; kk < 2; ++kk)
                    acc[m + 4][n] = __builtin_amdgcn_mfma_f32_16x16x32_bf16(
                        a[m][kk], bfr[n][kk], acc[m + 4][n], 0, 0, 0);
        __builtin_amdgcn_s_setprio(0);
        BAR();

        // phase 4: stage B.h1(t+2); vmcnt(4) once per tile
        if (t + 2 < 16) stageHalf(Bp, 1, 1, t + 2, bb);
        BAR();
        __builtin_amdgcn_s_setprio(1);
#pragma unroll
        for (int m = 0; m < 4; ++m)
#pragma unroll
            for (int n = 2; n < 4; ++n)
#pragma unroll
                for (int kk = 0; kk < 2; ++kk)
                    acc[m + 4][n] = __builtin_amdgcn_mfma_f32_16x16x32_bf16(
                        a[m][kk], bfr[n][kk], acc[m + 4][n], 0, 0, 0);
        __builtin_amdgcn_s_setprio(0);
        if (t < 14) {
            asm volatile("s_waitcnt vmcnt(4)" ::: "memory");
        } else if (t == 14) {
            asm volatile("s_waitcnt vmcnt(0)" ::: "memory");
        }
        BAR();
    }

    // epilogue
#pragma unroll
    for (int m = 0; m < 8; ++m) {
#pragma unroll
        for (int n = 0; n < 4; ++n) {
            const int col = tn * 256 + wn * 64 + n * 16 + l15;
            float bv_ = 0.f;
            if (EPI == 6 || EPI == 7) bv_ = bias[col];
#pragma unroll
            for (int j = 0; j < 4; ++j) {
                const int rowg = tm * 256 + wm * 128 + m * 16 + lq * 4 + j;
                const size_t idx = (size_t)rowg * Dk + col;
                const float xv = acc[m][n][j];
                if constexpr (EPI == 0) {
                    ((__hip_bfloat16*)CoutV)[idx] =
                        __float2bfloat16(xv * sigmoidf_fast(xv));
                } else if constexpr (EPI == 1) {
                    ((float*)CoutV)[idx] = xv;
                } else if constexpr (EPI == 6) {
                    const float e = FAST_EXP2(-(xv + bv_) * LOG2E);
                    ((__hip_bfloat16*)CoutV)[idx] = __float2bfloat16(e);
                } else {   // EPI == 7: Vt = tanh(x+b_v) * nl2 (pre-scaled)
                    const float y = xv + bv_;
                    const float e = FAST_EXP2(fabsf(y) * (2.f * LOG2E));
                    float tv = 1.f - 2.f * FAST_RCP(e + 1.f);
                    tv = copysignf(tv, y);
                    float nl2 = -dal[col] * LOG2E;
                    if (fabsf(nl2) < 1e-18f) nl2 = -1e-18f;
                    ((__hip_bfloat16*)CoutV)[idx] = __float2bfloat16(tv * nl2);
                }
            }
        }
    }
}

// Producer-consumer scan v5: 64 blocks x 3 waves, CH=64, TWO CHAINS PER
// PRODUCER LANE (d and d+64) interleaved for trans-latency hiding.
// Wave 0: 2 recurrence chains; waves 1-2: one d-column each (0-63 / 64-127),
// cell = h^2*sigmoid(h) + store. ht handoff via transposed padded lHT.
#define HPAD 68   // floats per d-row (64 + 4 pad)
__global__ __launch_bounds__(192)
void scan_kernel(const __hip_bfloat16* __restrict__ Eb,
                 const __hip_bfloat16* __restrict__ Vtb,
                 const float* __restrict__ h0,
                 const float* __restrict__ dal,
                 __hip_bfloat16* __restrict__ cell, float* __restrict__ hfin)
{
    constexpr int CH  = 64;
    constexpr int NCH = TT / CH;   // 32
    __shared__ __align__(16) unsigned short lE [2][CH * 128];  // 32KB
    __shared__ __align__(16) unsigned short lVt[2][CH * 128];  // 32KB
    __shared__ __align__(16) float lHT[2][128 * HPAD];         // ~70KB

    const int tid  = threadIdx.x;         // 0..191
    const int wave = tid >> 6;
    const int lane = tid & 63;
    const int bx   = blockIdx.x;          // 0..63
    const int b    = bx >> 3;             // 0..7
    const int d0   = (bx & 7) * 128;

    const size_t sbase = (size_t)b * TT * Dk + d0;   // bf16-element base

    if (wave == 0) {
        // ---------------- producer: two interleaved chains ----------------
        const int da = d0 + lane, db = da + 64;
        const int ga = b * Dk + da, gb = ga + 64;
        float nl2a = -dal[da] * LOG2E;
        if (fabsf(nl2a) < 1e-18f) nl2a = -1e-18f;
        float nl2b = -dal[db] * LOG2E;
        if (fabsf(nl2b) < 1e-18f) nl2b = -1e-18f;
        float ht0 = h0[ga] * nl2a;
        float ht1 = h0[gb] * nl2b;

        const int sl = lane >> 4;          // step within 4-group
        const int co = (lane & 15) * 8;    // u16 col offset (0..120)
        auto issue = [&](int ck, int buf) {
#pragma unroll
            for (int grp = 0; grp < 16; ++grp) {
                const size_t off = sbase + (size_t)(ck * CH + grp * 4 + sl) * Dk + co;
                gload_lds16(Eb  + off, (void*)&lE [buf][grp * 512]);
                gload_lds16(Vtb + off, (void*)&lVt[buf][grp * 512]);
            }
        };

        issue(0, 0);
        for (int k = 0; k < NCH; ++k) {
            const int buf = k & 1;
            asm volatile("s_waitcnt vmcnt(0)" ::: "memory");
            if (k + 1 < NCH) issue(k + 1, buf ^ 1);
            __builtin_amdgcn_sched_barrier(0);

#pragma unroll
            for (int g8 = 0; g8 < 8; ++g8) {
                float h0s[8], h1s[8];
#pragma unroll
                for (int j = 0; j < 8; ++j) {
                    const int s = g8 * 8 + j;
                    const float E0 = __uint_as_float(
                        (unsigned)lE [buf][s * 128 + lane] << 16);
                    const float V0 = __uint_as_float(
                        (unsigned)lVt[buf][s * 128 + lane] << 16);
                    const float E1 = __uint_as_float(
                        (unsigned)lE [buf][s * 128 + 64 + lane] << 16);
                    const float V1 = __uint_as_float(
                        (unsigned)lVt[buf][s * 128 + 64 + lane] << 16);
                    const float u0 = FAST_EXP2(ht0);
                    const float u1 = FAST_EXP2(ht1);
                    const float a0 = FAST_RCP(fmaf(E0, u0, 1.f));
                    const float a1 = FAST_RCP(fmaf(E1, u1, 1.f));
                    ht0 = fmaf(a0, ht0 - V0, V0);
                    ht1 = fmaf(a1, ht1 - V1, V1);
                    h0s[j] = ht0;
                    h1s[j] = ht1;
                }
                *(f32x4*)&lHT[buf][lane * HPAD + g8 * 8] =
                    (f32x4){h0s[0], h0s[1], h0s[2], h0s[3]};
                *(f32x4*)&lHT[buf][lane * HPAD + g8 * 8 + 4] =
                    (f32x4){h0s[4], h0s[5], h0s[6], h0s[7]};
                *(f32x4*)&lHT[buf][(64 + lane) * HPAD + g8 * 8] =
                    (f32x4){h1s[0], h1s[1], h1s[2], h1s[3]};
                *(f32x4*)&lHT[buf][(64 + lane) * HPAD + g8 * 8 + 4] =
                    (f32x4){h1s[4], h1s[5], h1s[6], h1s[7]};
            }
            asm volatile("s_waitcnt lgkmcnt(0)" ::: "memory");
            __builtin_amdgcn_s_barrier();
        }
        hfin[ga] = ht0 / nl2a;
        hfin[gb] = ht1 / nl2b;
    } else {
        // -------- consumers: one d-column each; cell = h^2*sigmoid(h) --------
        const int dl = (wave - 1) * 64 + lane;   // 0..127
        const int dc = d0 + dl;
        float nl2 = -dal[dc] * LOG2E;
        if (fabsf(nl2) < 1e-18f) nl2 = -1e-18f;
        const float inv  = 1.f / nl2;
        const float c1   = -inv * LOG2E;          // exp2(ht*c1) = exp(-h)
        const float inv2 = inv * inv;

        for (int k = 0; k < NCH; ++k) {
            __builtin_amdgcn_s_barrier();
            const int buf = k & 1;
            const size_t cb2 = sbase + (size_t)(k * CH) * Dk + dl;
#pragma unroll
            for (int g8 = 0; g8 < 8; ++g8) {
                const f32x4 v0 = *(const f32x4*)&lHT[buf][dl * HPAD + g8 * 8];
                const f32x4 v1 = *(const f32x4*)&lHT[buf][dl * HPAD + g8 * 8 + 4];
                float hv[8] = {v0[0], v0[1], v0[2], v0[3],
                               v1[0], v1[1], v1[2], v1[3]};
#pragma unroll
                for (int j = 0; j < 8; ++j) {
                    const float ht = hv[j];
                    const float sg = FAST_RCP(1.f + FAST_EXP2(ht * c1));
                    cell[cb2 + (size_t)(g8 * 8 + j) * Dk] =
                        __float2bfloat16(ht * ht * inv2 * sg);
                }
            }
        }
    }
}

extern "C" void kernel_launch(void* const* d_in, const int* in_sizes, int n_in,
                              void* d_out, int out_size, void* d_ws, size_t ws_size,
                              hipStream_t stream)
{
    const float* x     = (const float*)d_in[0];
    const float* h0    = (const float*)d_in[1];
    const float* W_in  = (const float*)d_in[2];
    const float* W_al  = (const float*)d_in[3];
    const float* d_al  = (const float*)d_in[4];
    const float* b_al  = (const float*)d_in[5];
    const float* W_x   = (const float*)d_in[6];
    const float* b_v   = (const float*)d_in[7];
    const float* W_out = (const float*)d_in[8];

    float* out  = (float*)d_out;
    float* hfin = out + (size_t)MROWS * Dk;

    char* ws = (char*)d_ws;
    const size_t bfBuf = (size_t)MROWS * Dk * sizeof(__hip_bfloat16);  // 33.5 MB
    const size_t wBuf  = (size_t)Dk * Dk * sizeof(__hip_bfloat16);     // 2 MB

    __hip_bfloat16* xb    = (__hip_bfloat16*)(ws);
    __hip_bfloat16* Winb  = (__hip_bfloat16*)(ws + bfBuf);
    __hip_bfloat16* Walb  = (__hip_bfloat16*)(ws + bfBuf + wBuf);
    __hip_bfloat16* Wxb   = (__hip_bfloat16*)(ws + bfBuf + 2 * wBuf);
    __hip_bfloat16* Woutb = (__hip_bfloat16*)(ws + bfBuf + 3 * wBuf);
    char* rest = ws + bfBuf + 4 * wBuf;
    __hip_bfloat16* xproj = (__hip_bfloat16*)rest;                 // then cell
    __hip_bfloat16* Ebuf  = (__hip_bfloat16*)(rest + bfBuf);       // 33.5 MB
    __hip_bfloat16* Vtbuf = (__hip_bfloat16*)(rest + 2 * bfBuf);   // 33.5 MB

    __hip_bfloat16* cellb = xproj;   // xproj dead after E/V GEMMs

    dim3 blk(256);
    cvt_all<<<dim3(16384 + 4096), blk, 0, stream>>>(
        x, W_in, W_al, W_x, W_out, xb, Winb, Walb, Wxb, Woutb);

    dim3 gblk(512), ggrid(256);
    gemm256<0><<<ggrid, gblk, 0, stream>>>(xb,    Winb,  nullptr, nullptr, xproj);
    gemm256<6><<<ggrid, gblk, 0, stream>>>(xproj, Walb,  b_al,    nullptr, Ebuf);
    gemm256<7><<<ggrid, gblk, 0, stream>>>(xproj, Wxb,   b_v,     d_al,    Vtbuf);
    scan_kernel<<<dim3(64), dim3(192), 0, stream>>>(Ebuf, Vtbuf, h0, d_al,
                                                    cellb, hfin);
    gemm256<1><<<ggrid, gblk, 0, stream>>>(cellb, Woutb, nullptr, nullptr, out);
}

// Round 17
// 239.342 us; speedup vs baseline: 1.2253x; 1.2253x over previous
//
#include <hip/hip_runtime.h>
#include <hip/hip_bf16.h>

typedef __attribute__((ext_vector_type(8))) short short8;
typedef __attribute__((ext_vector_type(4))) short short4v;
typedef __attribute__((ext_vector_type(4))) float f32x4;

#define Dk 1024
#define TT 2048
#define BB 8
#define MROWS (BB * TT)   // 16384
#define LOG2E 1.44269504088896f

#if defined(__has_builtin)
#if __has_builtin(__builtin_amdgcn_rcpf)
#define FAST_RCP(x) __builtin_amdgcn_rcpf(x)
#endif
#if __has_builtin(__builtin_amdgcn_exp2f)
#define FAST_EXP2(x) __builtin_amdgcn_exp2f(x)
#endif
#endif
#ifndef FAST_RCP
#define FAST_RCP(x) (1.f / (x))
#endif
#ifndef FAST_EXP2
#define FAST_EXP2(x) exp2f(x)
#endif

#define BAR()   __builtin_amdgcn_s_barrier()
#define LGKM0() do { asm volatile("s_waitcnt lgkmcnt(0)" ::: "memory"); \
                     __builtin_amdgcn_sched_barrier(0); } while (0)

__device__ __forceinline__ void gload_lds16(const void* g, void* l) {
    __builtin_amdgcn_global_load_lds(
        (const __attribute__((address_space(1))) void*)g,
        (__attribute__((address_space(3))) void*)l, 16, 0, 0);
}

__device__ __forceinline__ float sigmoidf_fast(float x) {
    return FAST_RCP(1.f + FAST_EXP2(-x * LOG2E));
}

__device__ __forceinline__ unsigned short bf16_bits(float x) {
    union { __hip_bfloat16 h; unsigned short u; } c;
    c.h = __float2bfloat16(x);
    return c.u;
}

// One launch converts x (16384 chunk-blocks) + 4 weights (1024 each).
__global__ __launch_bounds__(256)
void cvt_all(const float* __restrict__ x,
             const float* __restrict__ w0, const float* __restrict__ w1,
             const float* __restrict__ w2, const float* __restrict__ w3,
             __hip_bfloat16* __restrict__ xo,
             __hip_bfloat16* __restrict__ o0, __hip_bfloat16* __restrict__ o1,
             __hip_bfloat16* __restrict__ o2, __hip_bfloat16* __restrict__ o3)
{
    const int bid = blockIdx.x;
    const float* in;
    __hip_bfloat16* out;
    int base;
    if (bid < 16384) {
        in = x; out = xo; base = bid * 1024;
    } else {
        const int wbid  = bid - 16384;
        const int which = wbid >> 10;
        in  = which == 0 ? w0 : which == 1 ? w1 : which == 2 ? w2 : w3;
        out = which == 0 ? o0 : which == 1 ? o1 : which == 2 ? o2 : o3;
        base = (wbid & 1023) * 1024;
    }
    const int i = base + threadIdx.x * 4;
    const float4 v = *(const float4*)(in + i);
    __hip_bfloat16 tmp[4];
    tmp[0] = __float2bfloat16(v.x);
    tmp[1] = __float2bfloat16(v.y);
    tmp[2] = __float2bfloat16(v.z);
    tmp[3] = __float2bfloat16(v.w);
    *(short4v*)(out + i) = *(const short4v*)tmp;
}

// 256x256-tile 8-wave GEMM, C = epi(A * B^T), 8-phase schedule (r14-proven).
// EPI: 0 silu->bf16 | 1 plain->f32 | 6 E=exp(-(x+b_al))->bf16 (contiguous)
//      7 Vt=tanh(x+b_v)*nl2->bf16 (contiguous)
template<int EPI>
__global__ __launch_bounds__(512)
void gemm256(const __hip_bfloat16* __restrict__ A,
             const __hip_bfloat16* __restrict__ Bw,
             const float* __restrict__ bias,
             const float* __restrict__ dal,     // EPI7 only
             void* __restrict__ CoutV)
{
    __shared__ __align__(16) char lds[2 * 65536];   // buf: A 32KB | B 32KB

    const int tid  = threadIdx.x;         // 0..511
    const int bid  = blockIdx.x;
    const int nbid = (bid & 7) * 32 + (bid >> 3);   // XCD swizzle (256%8==0)
    const int tn   = nbid & 3;            // 4 col tiles
    const int tm   = nbid >> 2;           // 64 row tiles
    const int lane = tid & 63;
    const int w    = tid >> 6;            // 0..7
    const int wm   = w >> 2;              // 0..1
    const int wn   = w & 3;               // 0..3
    const int l15  = lane & 15;
    const int lq   = lane >> 4;

    const __hip_bfloat16* Ap = A  + (size_t)(tm * 256) * Dk;
    const __hip_bfloat16* Bp = Bw + (size_t)(tn * 256) * Dk;

    const int rA = wm * 16384 + l15 * 128;
    const int rB = 32768 + wn * 8192 + l15 * 128;
    int c8k[2];
    c8k[0] = ((lq    ) ^ (l15 & 7)) * 16;
    c8k[1] = ((lq + 4) ^ (l15 & 7)) * 16;

    const int srow = tid >> 3;
    const int scol = ((tid & 7) ^ (srow & 7)) * 8;

    auto stageHalf = [&](const __hip_bfloat16* src0, int reg, int h, int kt, int bb) {
#pragma unroll
        for (int j = 0; j < 2; ++j) {
            const int row  = h * 128 + j * 64 + srow;
            const int slot = h * 1024 + j * 512 + tid;
            gload_lds16(src0 + (size_t)row * Dk + kt * 64 + scol,
                        (char*)lds + bb + reg * 32768 + slot * 16);
        }
    };

    f32x4 acc[8][4];
#pragma unroll
    for (int m = 0; m < 8; ++m)
#pragma unroll
        for (int n = 0; n < 4; ++n)
            acc[m][n] = (f32x4){0.f, 0.f, 0.f, 0.f};

    stageHalf(Ap, 0, 0, 0, 0);      stageHalf(Ap, 0, 1, 0, 0);
    stageHalf(Bp, 1, 0, 0, 0);      stageHalf(Bp, 1, 1, 0, 0);
    stageHalf(Bp, 1, 0, 1, 65536);  stageHalf(Bp, 1, 1, 1, 65536);
    asm volatile("s_waitcnt vmcnt(4)" ::: "memory");
    BAR();

    short8 a[4][2], bfr[4][2];

    for (int t = 0; t < 16; ++t) {
        const int bb = (t & 1) * 65536;
        const int nb = bb ^ 65536;
        const char* cb = (const char*)lds + bb;

        // phase 1: A m0-3 + B n0-1 reads; stage A.h0(t+1)
#pragma unroll
        for (int m = 0; m < 4; ++m)
#pragma unroll
            for (int kk = 0; kk < 2; ++kk)
                a[m][kk] = *(const short8*)(cb + rA + m * 2048 + c8k[kk]);
#pragma unroll
        for (int n = 0; n < 2; ++n)
#pragma unroll
            for (int kk = 0; kk < 2; ++kk)
                bfr[n][kk] = *(const short8*)(cb + rB + n * 2048 + c8k[kk]);
        if (t + 1 < 16) stageHalf(Ap, 0, 0, t + 1, nb);
        BAR(); LGKM0();
        __builtin_amdgcn_s_setprio(1);
#pragma unroll
        for (int m = 0; m < 4; ++m)
#pragma unroll
            for (int n = 0; n < 2; ++n)
#pragma unroll
                for (int kk = 0; kk < 2; ++kk)
                    acc[m][n] = __builtin_amdgcn_mfma_f32_16x16x32_bf16(
                        a[m][kk], bfr[n][kk], acc[m][n], 0, 0, 0);
        __builtin_amdgcn_s_setprio(0);
        BAR();

        // phase 2: B n2-3 reads; stage A.h1(t+1)
#pragma unroll
        for (int n = 2; n < 4; ++n)
#pragma unroll
            for (int kk = 0; kk < 2; ++kk)
                bfr[n][kk] = *(const short8*)(cb + rB + n * 2048 + c8k[kk]);
        if (t + 1 < 16) stageHalf(Ap, 0, 1, t + 1, nb);
        BAR(); LGKM0();
        __builtin_amdgcn_s_setprio(1);
#pragma unroll
        for (int m = 0; m < 4; ++m)
#pragma unroll
            for (int n = 2; n < 4; ++n)
#pragma unroll
                for (int kk = 0; kk < 2; ++kk)
                    acc[m][n] = __builtin_amdgcn_mfma_f32_16x16x32_bf16(
                        a[m][kk], bfr[n][kk], acc[m][n], 0, 0, 0);
        __builtin_amdgcn_s_setprio(0);
        BAR();

        // phase 3: A m4-7 reads (reuse regs); stage B.h0(t+2)
#pragma unroll
        for (int m = 0; m < 4; ++m)
#pragma unroll
            for (int kk = 0; kk < 2; ++kk)
                a[m][kk] = *(const short8*)(cb + rA + (m + 4) * 2048 + c8k[kk]);
        if (t + 2 < 16) stageHalf(Bp, 1, 0, t + 2, bb);
        BAR(); LGKM0();
        __builtin_amdgcn_s_setprio(1);
#pragma unroll
        for (int m = 0; m < 4; ++m)
#pragma unroll
            for (int n = 0; n < 2; ++n)
#pragma unroll
                for (int kk = 0; kk < 2; ++kk)
                    acc[m + 4][n] = __builtin_amdgcn_mfma_f32_16x16x32_bf16(
                        a[m][kk], bfr[n][kk], acc[m + 4][n], 0, 0, 0);
        __builtin_amdgcn_s_setprio(0);
        BAR();

        // phase 4: stage B.h1(t+2); vmcnt(4) once per tile
        if (t + 2 < 16) stageHalf(Bp, 1, 1, t + 2, bb);
        BAR();
        __builtin_amdgcn_s_setprio(1);
#pragma unroll
        for (int m = 0; m < 4; ++m)
#pragma unroll
            for (int n = 2; n < 4; ++n)
#pragma unroll
                for (int kk = 0; kk < 2; ++kk)
                    acc[m + 4][n] = __builtin_amdgcn_mfma_f32_16x16x32_bf16(
                        a[m][kk], bfr[n][kk], acc[m + 4][n], 0, 0, 0);
        __builtin_amdgcn_s_setprio(0);
        if (t < 14) {
            asm volatile("s_waitcnt vmcnt(4)" ::: "memory");
        } else if (t == 14) {
            asm volatile("s_waitcnt vmcnt(0)" ::: "memory");
        }
        BAR();
    }

    // epilogue
#pragma unroll
    for (int m = 0; m < 8; ++m) {
#pragma unroll
        for (int n = 0; n < 4; ++n) {
            const int col = tn * 256 + wn * 64 + n * 16 + l15;
            float bv_ = 0.f;
            if (EPI == 6 || EPI == 7) bv_ = bias[col];
#pragma unroll
            for (int j = 0; j < 4; ++j) {
                const int rowg = tm * 256 + wm * 128 + m * 16 + lq * 4 + j;
                const size_t idx = (size_t)rowg * Dk + col;
                const float xv = acc[m][n][j];
                if constexpr (EPI == 0) {
                    ((__hip_bfloat16*)CoutV)[idx] =
                        __float2bfloat16(xv * sigmoidf_fast(xv));
                } else if constexpr (EPI == 1) {
                    ((float*)CoutV)[idx] = xv;
                } else if constexpr (EPI == 6) {
                    const float e = FAST_EXP2(-(xv + bv_) * LOG2E);
                    ((__hip_bfloat16*)CoutV)[idx] = __float2bfloat16(e);
                } else {   // EPI == 7: Vt = tanh(x+b_v) * nl2 (pre-scaled)
                    const float y = xv + bv_;
                    const float e = FAST_EXP2(fabsf(y) * (2.f * LOG2E));
                    float tv = 1.f - 2.f * FAST_RCP(e + 1.f);
                    tv = copysignf(tv, y);
                    float nl2 = -dal[col] * LOG2E;
                    if (fabsf(nl2) < 1e-18f) nl2 = -1e-18f;
                    ((__hip_bfloat16*)CoutV)[idx] = __float2bfloat16(tv * nl2);
                }
            }
        }
    }
}

// Producer-consumer scan v6 = r15 structure on split E/Vt streams.
// 128 blocks x 3 waves, CH=64, 1 chain/lane. Producer: per 8-step group,
// ALL 16 u16 reads batched BEFORE the chain ops (in-order-issue discipline),
// then 8 pure-VALU chain steps, then 2x b128 writes to transposed padded lHT.
// Consumers: 2 waves split steps 32/32, cell = h^2*sigmoid(h), store.
#define HPAD 68   // floats per lane row (64 + 4 pad)
__global__ __launch_bounds__(192)
void scan_kernel(const __hip_bfloat16* __restrict__ Eb,
                 const __hip_bfloat16* __restrict__ Vtb,
                 const float* __restrict__ h0,
                 const float* __restrict__ dal,
                 __hip_bfloat16* __restrict__ cell, float* __restrict__ hfin)
{
    constexpr int CH  = 64;
    constexpr int NCH = TT / CH;   // 32
    __shared__ __align__(16) unsigned short lE [2][CH * 64];   // 16KB
    __shared__ __align__(16) unsigned short lVt[2][CH * 64];   // 16KB
    __shared__ __align__(16) float lHT[2][64 * HPAD];          // ~35KB

    const int tid  = threadIdx.x;         // 0..191
    const int wave = tid >> 6;
    const int lane = tid & 63;
    const int bx   = blockIdx.x;          // 0..127
    const int b    = bx >> 4;
    const int d0   = (bx & 15) * 64;
    const int d    = d0 + lane;
    const int g    = b * Dk + d;

    float nl2 = -dal[d] * LOG2E;
    if (fabsf(nl2) < 1e-18f) nl2 = -1e-18f;
    const float inv_nl2 = 1.f / nl2;

    const size_t sbase = (size_t)b * TT * Dk + d0;

    if (wave == 0) {
        // ---------------- producer: the recurrence chain ----------------
        float ht = h0[g] * nl2;

        const int sl = lane >> 3;          // step-in-group 0..7
        const int co = (lane & 7) * 8;     // u16 col offset within 64-wide row
        auto issue = [&](int ck, int buf) {
#pragma unroll
            for (int grp = 0; grp < 8; ++grp) {
                const size_t off = sbase + (size_t)(ck * CH + grp * 8 + sl) * Dk + co;
                gload_lds16(Eb  + off, (void*)&lE [buf][grp * 512]);
                gload_lds16(Vtb + off, (void*)&lVt[buf][grp * 512]);
            }
        };

        issue(0, 0);
        for (int k = 0; k < NCH; ++k) {
            const int buf = k & 1;
            asm volatile("s_waitcnt vmcnt(0)" ::: "memory");
            if (k + 1 < NCH) issue(k + 1, buf ^ 1);
            __builtin_amdgcn_sched_barrier(0);

#pragma unroll
            for (int g8 = 0; g8 < 8; ++g8) {
                // batch ALL reads for the group before any chain op
                unsigned short e16[8], v16[8];
#pragma unroll
                for (int j = 0; j < 8; ++j) {
                    e16[j] = lE [buf][(g8 * 8 + j) * 64 + lane];
                    v16[j] = lVt[buf][(g8 * 8 + j) * 64 + lane];
                }
                float hts[8];
#pragma unroll
                for (int j = 0; j < 8; ++j) {
                    const float E  = __uint_as_float((unsigned)e16[j] << 16);
                    const float Vt = __uint_as_float((unsigned)v16[j] << 16);
                    const float u  = FAST_EXP2(ht);
                    const float al = FAST_RCP(fmaf(E, u, 1.f));
                    ht = fmaf(al, ht - Vt, Vt);
                    hts[j] = ht;
                }
                *(f32x4*)&lHT[buf][lane * HPAD + g8 * 8] =
                    (f32x4){hts[0], hts[1], hts[2], hts[3]};
                *(f32x4*)&lHT[buf][lane * HPAD + g8 * 8 + 4] =
                    (f32x4){hts[4], hts[5], hts[6], hts[7]};
            }
            asm volatile("s_waitcnt lgkmcnt(0)" ::: "memory");
            __builtin_amdgcn_s_barrier();
        }
        hfin[g] = ht * inv_nl2;
    } else {
        // -------- consumers: cell = h^2*sigmoid(h), strength-reduced --------
        const float c1   = -inv_nl2 * LOG2E;           // exp2(ht*c1) = exp(-h)
        const float inv2 = inv_nl2 * inv_nl2;
        const int   s0   = (wave - 1) * 32;
        for (int k = 0; k < NCH; ++k) {
            __builtin_amdgcn_s_barrier();
            const int buf = k & 1;
            const size_t cbase = sbase + (size_t)(k * CH) * Dk + lane;
#pragma unroll
            for (int g8 = 0; g8 < 4; ++g8) {
                const int s = s0 + g8 * 8;
                const f32x4 h0v = *(const f32x4*)&lHT[buf][lane * HPAD + s];
                const f32x4 h1v = *(const f32x4*)&lHT[buf][lane * HPAD + s + 4];
                float htv[8] = {h0v[0], h0v[1], h0v[2], h0v[3],
                                h1v[0], h1v[1], h1v[2], h1v[3]};
#pragma unroll
                for (int j = 0; j < 8; ++j) {
                    const float ht = htv[j];
                    const float sg = FAST_RCP(1.f + FAST_EXP2(ht * c1));
                    cell[cbase + (size_t)(s + j) * Dk] =
                        __float2bfloat16(ht * ht * inv2 * sg);
                }
            }
        }
    }
}

extern "C" void kernel_launch(void* const* d_in, const int* in_sizes, int n_in,
                              void* d_out, int out_size, void* d_ws, size_t ws_size,
                              hipStream_t stream)
{
    const float* x     = (const float*)d_in[0];
    const float* h0    = (const float*)d_in[1];
    const float* W_in  = (const float*)d_in[2];
    const float* W_al  = (const float*)d_in[3];
    const float* d_al  = (const float*)d_in[4];
    const float* b_al  = (const float*)d_in[5];
    const float* W_x   = (const float*)d_in[6];
    const float* b_v   = (const float*)d_in[7];
    const float* W_out = (const float*)d_in[8];

    float* out  = (float*)d_out;
    float* hfin = out + (size_t)MROWS * Dk;

    char* ws = (char*)d_ws;
    const size_t bfBuf = (size_t)MROWS * Dk * sizeof(__hip_bfloat16);  // 33.5 MB
    const size_t wBuf  = (size_t)Dk * Dk * sizeof(__hip_bfloat16);     // 2 MB

    __hip_bfloat16* xb    = (__hip_bfloat16*)(ws);
    __hip_bfloat16* Winb  = (__hip_bfloat16*)(ws + bfBuf);
    __hip_bfloat16* Walb  = (__hip_bfloat16*)(ws + bfBuf + wBuf);
    __hip_bfloat16* Wxb   = (__hip_bfloat16*)(ws + bfBuf + 2 * wBuf);
    __hip_bfloat16* Woutb = (__hip_bfloat16*)(ws + bfBuf + 3 * wBuf);
    char* rest = ws + bfBuf + 4 * wBuf;
    __hip_bfloat16* xproj = (__hip_bfloat16*)rest;                 // then cell
    __hip_bfloat16* Ebuf  = (__hip_bfloat16*)(rest + bfBuf);       // 33.5 MB
    __hip_bfloat16* Vtbuf = (__hip_bfloat16*)(rest + 2 * bfBuf);   // 33.5 MB

    __hip_bfloat16* cellb = xproj;   // xproj dead after E/V GEMMs

    dim3 blk(256);
    cvt_all<<<dim3(16384 + 4096), blk, 0, stream>>>(
        x, W_in, W_al, W_x, W_out, xb, Winb, Walb, Wxb, Woutb);

    dim3 gblk(512), ggrid(256);
    gemm256<0><<<ggrid, gblk, 0, stream>>>(xb,    Winb,  nullptr, nullptr, xproj);
    gemm256<6><<<ggrid, gblk, 0, stream>>>(xproj, Walb,  b_al,    nullptr, Ebuf);
    gemm256<7><<<ggrid, gblk, 0, stream>>>(xproj, Wxb,   b_v,     d_al,    Vtbuf);
    scan_kernel<<<dim3(128), dim3(192), 0, stream>>>(Ebuf, Vtbuf, h0, d_al,
                                                     cellb, hfin);
    gemm256<1><<<ggrid, gblk, 0, stream>>>(cellb, Woutb, nullptr, nullptr, out);
}